// Round 6
// baseline (73.161 us; speedup 1.0000x reference)
//
#include <hip/hip_runtime.h>
#include <hip/hip_bf16.h>

// ROUND 6: measurement round. R4's fused kernel (best: 67.0 us total),
// launched TWICE back-to-back. Launch 2 sees all inputs L3-warm, so
// total_R6 - total_R4 = exact warm-kernel duration (separates cold-memory
// cost H1 from intrinsic-kernel cost H2). Identical work both launches ->
// graph-capture safe, idempotent output.

// Problem constants (reference: B=128, K=2048, D=512, c=1.0)
#define B_SZ 128
#define K_SZ 2048
#define D_SZ 512
#define ROWP 520  // padded LDS row stride in bf16 (1040 B = 65 x 16B chunks,
                  // 65 % 8 == 1 -> 16 rows cycle all 8 bank-quads: b128
                  // fragment reads are perfectly bank-balanced)

typedef __attribute__((ext_vector_type(8))) short short8;   // 8 bf16
typedef __attribute__((ext_vector_type(4))) float floatx4;  // MFMA acc

// Manual RNE fp32 -> bf16.
static __device__ inline unsigned short f2b(float f) {
  unsigned int u = __float_as_uint(f);
  return (unsigned short)((u + 0x7fffu + ((u >> 16) & 1u)) >> 16);
}

// Fused kernel (identical to R4): stage x/p/a tiles fp32->bf16 into LDS
// while computing per-row stats in fp32, dual bf16-MFMA GEMM, LDS partial
// combine, fused hyperbolic-MLR epilogue.
// Block = 32 b x 16 k. Grid = 512 = 2 blocks/CU (LDS 65.3 KB). 4 waves:
// wave w -> m-half (w&1), d-half (w>>1).
__global__ __launch_bounds__(256, 2) void fused_kernel(
    const float* __restrict__ x, const float* __restrict__ p,
    const float* __restrict__ a, float* __restrict__ out) {
  __shared__ unsigned short xs[32 * ROWP];   // 33280 B
  __shared__ unsigned short ps[16 * ROWP];   // 16640 B (partials alias here)
  __shared__ unsigned short as_[16 * ROWP];  // 16640 B
  __shared__ float stats[32 + 48];           // vv[32] | uu[16] | nua[16] | an[16]

  const int t = threadIdx.x;
  const int bm = (blockIdx.x >> 7) * 32;   // 4 m-tiles of 32 b
  const int kn = (blockIdx.x & 127) * 16;  // 128 k-tiles of 16 k

  // ---- Phase 0a: stage x (32 rows), vv stats. 8 threads/row, 16 float4 ea.
  {
    const int r = t >> 3, s = t & 7;
    const float4* src = (const float4*)(x + (size_t)(bm + r) * D_SZ);
    float vvp = 0.f;
#pragma unroll
    for (int i = 0; i < 16; ++i) {
      float4 v = src[s + i * 8];
      vvp += v.x * v.x + v.y * v.y + v.z * v.z + v.w * v.w;
      ushort4 c;
      c.x = f2b(v.x); c.y = f2b(v.y); c.z = f2b(v.z); c.w = f2b(v.w);
      *(ushort4*)&xs[r * ROWP + (s + i * 8) * 4] = c;
    }
    vvp += __shfl_xor(vvp, 1, 64);
    vvp += __shfl_xor(vvp, 2, 64);
    vvp += __shfl_xor(vvp, 4, 64);
    if (s == 0) stats[r] = vvp;
  }

  // ---- Phase 0b: stage p,a (16 rows), uu/nua/an stats. 16 thr/row, 8 f4 ea.
  {
    const int r = t >> 4, s = t & 15;
    const float4* sp = (const float4*)(p + (size_t)(kn + r) * D_SZ);
    const float4* sa = (const float4*)(a + (size_t)(kn + r) * D_SZ);
    float pp = 0.f, pa = 0.f, aa = 0.f;
#pragma unroll
    for (int i = 0; i < 8; ++i) {
      float4 pv = sp[s + i * 16];
      float4 av = sa[s + i * 16];
      pp += pv.x * pv.x + pv.y * pv.y + pv.z * pv.z + pv.w * pv.w;
      pa += pv.x * av.x + pv.y * av.y + pv.z * av.z + pv.w * av.w;
      aa += av.x * av.x + av.y * av.y + av.z * av.z + av.w * av.w;
      ushort4 pc, ac;
      pc.x = f2b(pv.x); pc.y = f2b(pv.y); pc.z = f2b(pv.z); pc.w = f2b(pv.w);
      ac.x = f2b(av.x); ac.y = f2b(av.y); ac.z = f2b(av.z); ac.w = f2b(av.w);
      *(ushort4*)&ps[r * ROWP + (s + i * 16) * 4] = pc;
      *(ushort4*)&as_[r * ROWP + (s + i * 16) * 4] = ac;
    }
    pp += __shfl_xor(pp, 1, 64);
    pa += __shfl_xor(pa, 1, 64);
    aa += __shfl_xor(aa, 1, 64);
    pp += __shfl_xor(pp, 2, 64);
    pa += __shfl_xor(pa, 2, 64);
    aa += __shfl_xor(aa, 2, 64);
    pp += __shfl_xor(pp, 4, 64);
    pa += __shfl_xor(pa, 4, 64);
    aa += __shfl_xor(aa, 4, 64);
    pp += __shfl_xor(pp, 8, 64);
    pa += __shfl_xor(pa, 8, 64);
    aa += __shfl_xor(aa, 8, 64);
    if (s == 0) {
      stats[32 + r] = pp;        // uu
      stats[48 + r] = -pa;       // nua
      stats[64 + r] = sqrtf(aa); // an
    }
  }
  __syncthreads();

  // ---- Phase 1: dual MFMA. wave w: m-half wm = w&1, d-half dh = w>>1.
  const int w = t >> 6, lane = t & 63;
  const int row16 = lane & 15, quad = lane >> 4;
  const int wm = w & 1, dh = w >> 1;
  const unsigned short* xrow = &xs[(wm * 16 + row16) * ROWP + dh * 256 + quad * 8];
  const unsigned short* prow = &ps[row16 * ROWP + dh * 256 + quad * 8];
  const unsigned short* arow = &as_[row16 * ROWP + dh * 256 + quad * 8];
  floatx4 cs = {0.f, 0.f, 0.f, 0.f};
  floatx4 ca = {0.f, 0.f, 0.f, 0.f};
#pragma unroll
  for (int dc = 0; dc < 8; ++dc) {
    short8 af = *(const short8*)(xrow + dc * 32);
    short8 bp = *(const short8*)(prow + dc * 32);
    short8 bv = *(const short8*)(arow + dc * 32);
    cs = __builtin_amdgcn_mfma_f32_16x16x32_bf16(af, bp, cs, 0, 0, 0);
    ca = __builtin_amdgcn_mfma_f32_16x16x32_bf16(af, bv, ca, 0, 0, 0);
  }

  // ---- Phase 2: combine d-halves through LDS (alias ps; done reading it).
  __syncthreads();
  float* part_s = (float*)ps;          // [4 waves][64 lanes][4 regs] = 4 KB
  float* part_a = part_s + 1024;       // 4 KB
  *(floatx4*)&part_s[(w * 64 + lane) * 4] = cs;
  *(floatx4*)&part_a[(w * 64 + lane) * 4] = ca;
  __syncthreads();

  // ---- Phase 3: epilogue, 2 outputs per thread (c = 1).
#pragma unroll
  for (int o = 0; o < 2; ++o) {
    const int idx = t + o * 256;   // 0..511 -> (m16, n)
    const int m16 = idx >> 4;      // 0..31 local b
    const int n = idx & 15;        // local k
    const int wmI = m16 >> 4, mr = m16 & 15;
    const int lsrc = ((mr >> 2) << 4) | n;
    const int reg = mr & 3;
    const float sdot = part_s[(wmI * 64 + lsrc) * 4 + reg] +
                       part_s[((2 + wmI) * 64 + lsrc) * 4 + reg];
    const float adot = part_a[(wmI * 64 + lsrc) * 4 + reg] +
                       part_a[((2 + wmI) * 64 + lsrc) * 4 + reg];
    const float vvb = stats[m16];
    const float uuk = stats[32 + n];
    const float nuak = stats[48 + n];
    const float ank = stats[64 + n];
    const float beta = 1.f - uuk;            // 1 - c*||p||^2
    const float scale = (2.f / beta) * ank;  // lam_p * ||a||
    const float uv = -sdot;                  // <u,x> = -<p,x>
    const float alpha = 1.f + 2.f * uv + vvb;
    const float den = 1.f + 2.f * uv + uuk * vvb;
    const float inv = 1.f / den;
    const float wwn =
        (alpha * alpha * uuk + 2.f * alpha * beta * uv + beta * beta * vvb) *
        inv * inv;
    const float wa = (alpha * nuak + beta * adot) * inv;
    const float z = 2.f * wa / (ank * (1.f - wwn));
    out[(size_t)(bm + m16) * K_SZ + (kn + n)] = scale * asinhf(z);
  }
}

extern "C" void kernel_launch(void* const* d_in, const int* in_sizes, int n_in,
                              void* d_out, int out_size, void* d_ws, size_t ws_size,
                              hipStream_t stream) {
  const float* x = (const float*)d_in[0];  // inp [B,D]
  const float* p = (const float*)d_in[1];  // p   [K,D]
  const float* a = (const float*)d_in[2];  // a   [K,D]
  float* out = (float*)d_out;              // [B,K] fp32
  (void)d_ws; (void)ws_size;               // no workspace needed

  // Launch 1: cold inputs (exactly R4's single launch).
  fused_kernel<<<(B_SZ / 32) * (K_SZ / 16), 256, 0, stream>>>(x, p, a, out);
  // Launch 2: identical work, inputs now L3-warm. Total - R4_total = warm
  // kernel duration -> decides cold-memory (H1) vs intrinsic-cost (H2).
  fused_kernel<<<(B_SZ / 32) * (K_SZ / 16), 256, 0, stream>>>(x, p, a, out);
}

// Round 8
// 68.018 us; speedup vs baseline: 1.0756x; 1.0756x over previous
//
#include <hip/hip_runtime.h>
#include <hip/hip_bf16.h>

// Problem constants (reference: B=128, K=2048, D=512, c=1.0)
#define B_SZ 128
#define K_SZ 2048
#define D_SZ 512
#define ROWP 520  // LDS row stride (bf16): 1040 B = 65 16B-granules, 65%8==1
                  // -> b128 fragment reads bank-balanced (validated R4/R6)

typedef __attribute__((ext_vector_type(8))) short short8;   // 8 bf16
typedef __attribute__((ext_vector_type(4))) float floatx4;  // MFMA acc / NT f4

// Manual RNE fp32 -> bf16.
static __device__ inline unsigned short f2b(float f) {
  unsigned int u = __float_as_uint(f);
  return (unsigned short)((u + 0x7fffu + ((u >> 16) & 1u)) >> 16);
}

// R7b: single fused kernel, NT-load variant (R7 with the compile fix:
// __builtin_nontemporal_load needs a native clang vector type, so NT
// accesses go through ext_vector_type float4, not HIP float4).
// Evidence (R6 A/B): warm kernel ~<=6 us, cold ~21 us -> ~15 us is input-
// temperature cost. Theory: the per-iteration 268 MB ws-poison fill leaves
// L2/L3 fully dirty; read-misses pay dirty-victim writeback stalls
// (0.56 TB/s effective). Fix attempt: NT loads for the 8 MB p/a stream
// (no cache allocation -> no victim eviction), 2x p/a replication via
// 64b x 16k blocks.
// Block = 64 b x 16 k; grid = 2*128 = 256 = 1 block/CU; 4 waves.
// Wave w owns m-rows [16w,16w+16) over FULL D -> no d-split, accumulators
// final, single barrier. LDS ~100 KB -> 1 block/CU.
// Fragment layouts (m89/m91-verified):
//   A/B: row = lane&15, d = quad*8 + j (16B/lane; row-major == B^T)
//   C/D: n = lane&15, m = quad*4 + reg
__global__ __launch_bounds__(256, 1) void fused_kernel(
    const float* __restrict__ x, const float* __restrict__ p,
    const float* __restrict__ a, float* __restrict__ out) {
  __shared__ unsigned short xs[64 * ROWP];   // 66560 B
  __shared__ unsigned short ps[16 * ROWP];   // 16640 B
  __shared__ unsigned short as_[16 * ROWP];  // 16640 B
  __shared__ float svv[64];                  // sum x^2 per b-row
  __shared__ float spp[16], spa[16], saa[16];  // p.p, p.a, a.a per k-row

  const int t = threadIdx.x;
  const int lane = t & 63;
  const int w = t >> 6;
  const int row16 = lane & 15;
  const int quad = lane >> 4;
  const int bm = (blockIdx.x >> 7) * 64;   // 2 m-blocks
  const int kn = (blockIdx.x & 127) * 16;  // 128 k-tiles (same-XCD pairs)

  // ---- Stage p,a via NT loads (16 thr/row, 8 f4 each) + stats.
  {
    const int r = t >> 4, s = t & 15;
    const floatx4* sp = (const floatx4*)(p + (size_t)(kn + r) * D_SZ);
    const floatx4* sa = (const floatx4*)(a + (size_t)(kn + r) * D_SZ);
    float pp = 0.f, pa = 0.f, aa = 0.f;
#pragma unroll
    for (int i = 0; i < 8; ++i) {
      floatx4 pv = __builtin_nontemporal_load(&sp[s + i * 16]);
      floatx4 av = __builtin_nontemporal_load(&sa[s + i * 16]);
      pp += pv[0] * pv[0] + pv[1] * pv[1] + pv[2] * pv[2] + pv[3] * pv[3];
      pa += pv[0] * av[0] + pv[1] * av[1] + pv[2] * av[2] + pv[3] * av[3];
      aa += av[0] * av[0] + av[1] * av[1] + av[2] * av[2] + av[3] * av[3];
      ushort4 pc, ac;
      pc.x = f2b(pv[0]); pc.y = f2b(pv[1]); pc.z = f2b(pv[2]); pc.w = f2b(pv[3]);
      ac.x = f2b(av[0]); ac.y = f2b(av[1]); ac.z = f2b(av[2]); ac.w = f2b(av[3]);
      *(ushort4*)&ps[r * ROWP + (s + i * 16) * 4] = pc;
      *(ushort4*)&as_[r * ROWP + (s + i * 16) * 4] = ac;
    }
    pp += __shfl_xor(pp, 1, 64); pa += __shfl_xor(pa, 1, 64);
    aa += __shfl_xor(aa, 1, 64);
    pp += __shfl_xor(pp, 2, 64); pa += __shfl_xor(pa, 2, 64);
    aa += __shfl_xor(aa, 2, 64);
    pp += __shfl_xor(pp, 4, 64); pa += __shfl_xor(pa, 4, 64);
    aa += __shfl_xor(aa, 4, 64);
    pp += __shfl_xor(pp, 8, 64); pa += __shfl_xor(pa, 8, 64);
    aa += __shfl_xor(aa, 8, 64);
    if (s == 0) { spp[r] = pp; spa[r] = pa; saa[r] = aa; }
  }

  // ---- Stage x via cached loads (L3-served; 4 thr/row, 32 f4 each) + vv.
  {
    const int r = t >> 2, s = t & 3;
    const float4* sx = (const float4*)(x + (size_t)(bm + r) * D_SZ);
    float vvp = 0.f;
#pragma unroll
    for (int i = 0; i < 32; ++i) {
      float4 v = sx[s + i * 4];
      vvp += v.x * v.x + v.y * v.y + v.z * v.z + v.w * v.w;
      ushort4 c;
      c.x = f2b(v.x); c.y = f2b(v.y); c.z = f2b(v.z); c.w = f2b(v.w);
      *(ushort4*)&xs[r * ROWP + (s + i * 4) * 4] = c;
    }
    vvp += __shfl_xor(vvp, 1, 64);
    vvp += __shfl_xor(vvp, 2, 64);
    if (s == 0) svv[r] = vvp;
  }
  __syncthreads();

  // ---- Dual MFMA: wave w, 16x16 tile (m-rows 16w..16w+15), full D.
  const unsigned short* xrow = &xs[(w * 16 + row16) * ROWP + quad * 8];
  const unsigned short* prow = &ps[row16 * ROWP + quad * 8];
  const unsigned short* arow = &as_[row16 * ROWP + quad * 8];
  floatx4 cs = {0.f, 0.f, 0.f, 0.f};
  floatx4 ca = {0.f, 0.f, 0.f, 0.f};
#pragma unroll
  for (int dc = 0; dc < 16; ++dc) {
    short8 af = *(const short8*)(xrow + dc * 32);
    short8 bp = *(const short8*)(prow + dc * 32);
    short8 bv = *(const short8*)(arow + dc * 32);
    cs = __builtin_amdgcn_mfma_f32_16x16x32_bf16(af, bp, cs, 0, 0, 0);
    ca = __builtin_amdgcn_mfma_f32_16x16x32_bf16(af, bv, ca, 0, 0, 0);
  }

  // ---- Epilogue (c = 1): 4 outputs per lane, NT stores.
  const int n = row16;
  const int k = kn + n;
  const float uuk = spp[n];
  const float nuak = -spa[n];
  const float ank = sqrtf(saa[n]);
  const float beta = 1.f - uuk;            // 1 - c*||p||^2
  const float scale = (2.f / beta) * ank;  // lam_p * ||a||
#pragma unroll
  for (int r = 0; r < 4; ++r) {
    const int m = w * 16 + quad * 4 + r;
    const float vvb = svv[m];
    const float uv = -cs[r];  // <u,x> = -<p,x>
    const float xa = ca[r];
    const float alpha = 1.f + 2.f * uv + vvb;
    const float den = 1.f + 2.f * uv + uuk * vvb;
    const float inv = 1.f / den;
    const float wwn =
        (alpha * alpha * uuk + 2.f * alpha * beta * uv + beta * beta * vvb) *
        inv * inv;
    const float wa = (alpha * nuak + beta * xa) * inv;
    const float z = 2.f * wa / (ank * (1.f - wwn));
    __builtin_nontemporal_store(scale * asinhf(z),
                                &out[(size_t)(bm + m) * K_SZ + k]);
  }
}

extern "C" void kernel_launch(void* const* d_in, const int* in_sizes, int n_in,
                              void* d_out, int out_size, void* d_ws, size_t ws_size,
                              hipStream_t stream) {
  const float* x = (const float*)d_in[0];  // inp [B,D]
  const float* p = (const float*)d_in[1];  // p   [K,D]
  const float* a = (const float*)d_in[2];  // a   [K,D]
  float* out = (float*)d_out;              // [B,K] fp32
  (void)d_ws; (void)ws_size;               // no workspace needed

  fused_kernel<<<(B_SZ / 64) * (K_SZ / 16), 256, 0, stream>>>(x, p, a, out);
}

// Round 9
// 67.872 us; speedup vs baseline: 1.0779x; 1.0021x over previous
//
#include <hip/hip_runtime.h>
#include <hip/hip_bf16.h>

// Problem constants (reference: B=128, K=2048, D=512, c=1.0)
#define B_SZ 128
#define K_SZ 2048
#define D_SZ 512
#define ROWP 520  // LDS row stride (bf16): 1040 B = 65 16B-granules, 65%8==1
                  // -> b128 fragment reads bank-balanced (validated R4/R6)

typedef __attribute__((ext_vector_type(8))) short short8;   // 8 bf16
typedef __attribute__((ext_vector_type(4))) float floatx4;  // MFMA acc

// Manual RNE fp32 -> bf16.
static __device__ inline unsigned short f2b(float f) {
  unsigned int u = __float_as_uint(f);
  return (unsigned short)((u + 0x7fffu + ((u >> 16) & 1u)) >> 16);
}

// R9: R4's fused kernel with MLP-forced staging.
// Evidence chain: R6 A/B -> cold-input cost ~15 us; R8 -> NT loads neutral;
// harness's own restores + m13 copy µbench -> cold HBM streams at 3-6 TB/s
// when loads are issued back-to-back. Diagnosis: R4-R8 staging interleaved
// dependent VALU (f2b/stats/LDS stores) with loads -> compiler waits on
// vmcnt every few loads -> ~0.5 TB/s. Fix: issue ALL 32 staging loads into
// register arrays first (x batch, then p/a batch), process after. First use
// waits only on the x batch; p/a loads remain in flight underneath.
// Everything else identical to R4 (validated absmax 7.8e-3).
// Block = 32 b x 16 k. Grid = 512 = 2 blocks/CU. 4 waves: wave w -> m-half
// (w&1), d-half (w>>1).
__global__ __launch_bounds__(256, 2) void fused_kernel(
    const float* __restrict__ x, const float* __restrict__ p,
    const float* __restrict__ a, float* __restrict__ out) {
  __shared__ unsigned short xs[32 * ROWP];   // 33280 B
  __shared__ unsigned short ps[16 * ROWP];   // 16640 B (partials alias here)
  __shared__ unsigned short as_[16 * ROWP];  // 16640 B
  __shared__ float stats[32 + 48];           // vv[32] | uu[16] | nua[16] | an[16]

  const int t = threadIdx.x;
  const int bm = (blockIdx.x >> 7) * 32;   // 4 m-tiles of 32 b
  const int kn = (blockIdx.x & 127) * 16;  // 128 k-tiles of 16 k

  // ---- Phase 0-issue: ALL staging loads back-to-back into registers.
  const int rx = t >> 3, sx_ = t & 7;    // x: 8 thr/row, 16 f4 each
  const int rp = t >> 4, sp_ = t & 15;   // p/a: 16 thr/row, 8 f4 each
  const float4* srcx = (const float4*)(x + (size_t)(bm + rx) * D_SZ);
  const float4* srcp = (const float4*)(p + (size_t)(kn + rp) * D_SZ);
  const float4* srca = (const float4*)(a + (size_t)(kn + rp) * D_SZ);
  float4 xf[16];
#pragma unroll
  for (int i = 0; i < 16; ++i) xf[i] = srcx[sx_ + i * 8];
  float4 pf[8], avf[8];
#pragma unroll
  for (int i = 0; i < 8; ++i) pf[i] = srcp[sp_ + i * 16];
#pragma unroll
  for (int i = 0; i < 8; ++i) avf[i] = srca[sp_ + i * 16];

  // ---- Phase 0a-process: x -> bf16 LDS + vv stats (waits only on x batch).
  {
    float vvp = 0.f;
#pragma unroll
    for (int i = 0; i < 16; ++i) {
      float4 v = xf[i];
      vvp += v.x * v.x + v.y * v.y + v.z * v.z + v.w * v.w;
      ushort4 c;
      c.x = f2b(v.x); c.y = f2b(v.y); c.z = f2b(v.z); c.w = f2b(v.w);
      *(ushort4*)&xs[rx * ROWP + (sx_ + i * 8) * 4] = c;
    }
    vvp += __shfl_xor(vvp, 1, 64);
    vvp += __shfl_xor(vvp, 2, 64);
    vvp += __shfl_xor(vvp, 4, 64);
    if (sx_ == 0) stats[rx] = vvp;
  }

  // ---- Phase 0b-process: p,a -> bf16 LDS + uu/nua/an stats.
  {
    float pp = 0.f, pa = 0.f, aa = 0.f;
#pragma unroll
    for (int i = 0; i < 8; ++i) {
      float4 pv = pf[i];
      float4 av = avf[i];
      pp += pv.x * pv.x + pv.y * pv.y + pv.z * pv.z + pv.w * pv.w;
      pa += pv.x * av.x + pv.y * av.y + pv.z * av.z + pv.w * av.w;
      aa += av.x * av.x + av.y * av.y + av.z * av.z + av.w * av.w;
      ushort4 pc, ac;
      pc.x = f2b(pv.x); pc.y = f2b(pv.y); pc.z = f2b(pv.z); pc.w = f2b(pv.w);
      ac.x = f2b(av.x); ac.y = f2b(av.y); ac.z = f2b(av.z); ac.w = f2b(av.w);
      *(ushort4*)&ps[rp * ROWP + (sp_ + i * 16) * 4] = pc;
      *(ushort4*)&as_[rp * ROWP + (sp_ + i * 16) * 4] = ac;
    }
    pp += __shfl_xor(pp, 1, 64);
    pa += __shfl_xor(pa, 1, 64);
    aa += __shfl_xor(aa, 1, 64);
    pp += __shfl_xor(pp, 2, 64);
    pa += __shfl_xor(pa, 2, 64);
    aa += __shfl_xor(aa, 2, 64);
    pp += __shfl_xor(pp, 4, 64);
    pa += __shfl_xor(pa, 4, 64);
    aa += __shfl_xor(aa, 4, 64);
    pp += __shfl_xor(pp, 8, 64);
    pa += __shfl_xor(pa, 8, 64);
    aa += __shfl_xor(aa, 8, 64);
    if (sp_ == 0) {
      stats[32 + rp] = pp;        // uu
      stats[48 + rp] = -pa;       // nua
      stats[64 + rp] = sqrtf(aa); // an
    }
  }
  __syncthreads();

  // ---- Phase 1: dual MFMA. wave w: m-half wm = w&1, d-half dh = w>>1.
  const int w = t >> 6, lane = t & 63;
  const int row16 = lane & 15, quad = lane >> 4;
  const int wm = w & 1, dh = w >> 1;
  const unsigned short* xrow = &xs[(wm * 16 + row16) * ROWP + dh * 256 + quad * 8];
  const unsigned short* prow = &ps[row16 * ROWP + dh * 256 + quad * 8];
  const unsigned short* arow = &as_[row16 * ROWP + dh * 256 + quad * 8];
  floatx4 cs = {0.f, 0.f, 0.f, 0.f};
  floatx4 ca = {0.f, 0.f, 0.f, 0.f};
#pragma unroll
  for (int dc = 0; dc < 8; ++dc) {
    short8 af = *(const short8*)(xrow + dc * 32);
    short8 bp = *(const short8*)(prow + dc * 32);
    short8 bv = *(const short8*)(arow + dc * 32);
    cs = __builtin_amdgcn_mfma_f32_16x16x32_bf16(af, bp, cs, 0, 0, 0);
    ca = __builtin_amdgcn_mfma_f32_16x16x32_bf16(af, bv, ca, 0, 0, 0);
  }

  // ---- Phase 2: combine d-halves through LDS (alias ps; done reading it).
  __syncthreads();
  float* part_s = (float*)ps;          // [4 waves][64 lanes][4 regs] = 4 KB
  float* part_a = part_s + 1024;       // 4 KB
  *(floatx4*)&part_s[(w * 64 + lane) * 4] = cs;
  *(floatx4*)&part_a[(w * 64 + lane) * 4] = ca;
  __syncthreads();

  // ---- Phase 3: epilogue, 2 outputs per thread (c = 1).
#pragma unroll
  for (int o = 0; o < 2; ++o) {
    const int idx = t + o * 256;   // 0..511 -> (m16, n)
    const int m16 = idx >> 4;      // 0..31 local b
    const int n = idx & 15;        // local k
    const int wmI = m16 >> 4, mr = m16 & 15;
    const int lsrc = ((mr >> 2) << 4) | n;
    const int reg = mr & 3;
    const float sdot = part_s[(wmI * 64 + lsrc) * 4 + reg] +
                       part_s[((2 + wmI) * 64 + lsrc) * 4 + reg];
    const float adot = part_a[(wmI * 64 + lsrc) * 4 + reg] +
                       part_a[((2 + wmI) * 64 + lsrc) * 4 + reg];
    const float vvb = stats[m16];
    const float uuk = stats[32 + n];
    const float nuak = stats[48 + n];
    const float ank = stats[64 + n];
    const float beta = 1.f - uuk;            // 1 - c*||p||^2
    const float scale = (2.f / beta) * ank;  // lam_p * ||a||
    const float uv = -sdot;                  // <u,x> = -<p,x>
    const float alpha = 1.f + 2.f * uv + vvb;
    const float den = 1.f + 2.f * uv + uuk * vvb;
    const float inv = 1.f / den;
    const float wwn =
        (alpha * alpha * uuk + 2.f * alpha * beta * uv + beta * beta * vvb) *
        inv * inv;
    const float wa = (alpha * nuak + beta * adot) * inv;
    const float z = 2.f * wa / (ank * (1.f - wwn));
    out[(size_t)(bm + m16) * K_SZ + (kn + n)] = scale * asinhf(z);
  }
}

extern "C" void kernel_launch(void* const* d_in, const int* in_sizes, int n_in,
                              void* d_out, int out_size, void* d_ws, size_t ws_size,
                              hipStream_t stream) {
  const float* x = (const float*)d_in[0];  // inp [B,D]
  const float* p = (const float*)d_in[1];  // p   [K,D]
  const float* a = (const float*)d_in[2];  // a   [K,D]
  float* out = (float*)d_out;              // [B,K] fp32
  (void)d_ws; (void)ws_size;               // no workspace needed

  fused_kernel<<<(B_SZ / 32) * (K_SZ / 16), 256, 0, stream>>>(x, p, a, out);
}